// Round 9
// baseline (159.117 us; speedup 1.0000x reference)
//
#include <hip/hip_runtime.h>

#define NBLK 256
#define POISON 0xAAAAAAAAu

// Exact (non-approximate) GELU, matching jax.nn.gelu(approximate=False).
__device__ __forceinline__ float gelu_exact(float x) {
    return 0.5f * x * (1.0f + erff(x * 0.7071067811865475f));
}

__device__ __forceinline__ float dot4(float4 a, float4 b) {
    return a.x * b.x + a.y * b.y + a.z * b.z + a.w * b.w;
}

// Full 64-lane wave reduce (sum).
__device__ __forceinline__ float wave_reduce(float acc) {
    #pragma unroll
    for (int off = 32; off >= 1; off >>= 1) acc += __shfl_xor(acc, off);
    return acc;
}

// Software grid barrier for exactly-NBLK-block grids that are guaranteed
// co-resident (NBLK=256 blocks of 256 thr, tiny VGPR/LDS -> capacity is
// ~8 blocks/CU x 256 CUs, 8x the requirement; dispatch placement cannot
// strand a block). Counter starts as harness 0xAA poison; the first
// arriving block CASes it to 0 (losers' CAS fails benignly: counter is
// 0..255, never equals POISON again). Arrive with device-scope atomicAdd;
// spin with agent-scope acquire loads (cross-XCD visible).
__device__ __forceinline__ void grid_barrier(unsigned* slot) {
    __syncthreads();
    if (threadIdx.x == 0) {
        atomicCAS(slot, POISON, 0u);
        __threadfence();                 // prior release-stores drained
        atomicAdd(slot, 1u);
        while (__hip_atomic_load(slot, __ATOMIC_ACQUIRE,
                                 __HIP_MEMORY_SCOPE_AGENT) < NBLK) {
            __builtin_amdgcn_s_sleep(4); // ~256cy backoff
        }
    }
    __syncthreads();
}

// Whole pipeline in ONE dispatch: 256 blocks x 256 threads.
// MLP phase: block j owns neuron j of each 256x256 layer (wave 0 does a
// coalesced float4 row load + butterfly reduce); x vectors ping-pong
// through d_ws with agent-scope release/acquire (per-XCD L2s are NOT
// coherent -- plain stores would strand dirty lines in the writer's L2).
// Apply phase: identical to the round-7 apply kernel (256 blk x 256 thr).
__global__ __launch_bounds__(256) void fused_kernel(
    const float* __restrict__ W1, const float* __restrict__ b1,
    const float* __restrict__ W2, const float* __restrict__ b2,
    const float* __restrict__ W3, const float* __restrict__ b3,
    const float* __restrict__ W4, const float* __restrict__ b4,
    const float* __restrict__ W5, const float* __restrict__ b5,
    const float* __restrict__ feat, float* __restrict__ out,
    float* __restrict__ ws)
{
    float*    wout = ws;                       // 12 floats
    float*    xA   = ws + 64;                  // 256 floats
    float*    xB   = ws + 64 + 256;            // 256 floats
    float*    xC   = ws + 64 + 512;            // 256 floats
    unsigned* bar  = (unsigned*)(ws + 64 + 768); // 4 slots, 128B apart

    __shared__ __align__(16) float xs[256];
    __shared__ float wl[12];

    const int t = threadIdx.x;
    const int j = blockIdx.x;        // 0..255 = neuron id in MLP phase
    const int w = t >> 6;            // wave 0..3
    const int l = t & 63;            // lane

    // ---- Layer 1 (redundant per block; W1 is 4KB, L2/L3-cached) ----
    // MLP input is [0,0,1,1]; W1 [256,4] row-major: pre = W1[t,2]+W1[t,3]+b1[t]
    {
        float4 w1r = *reinterpret_cast<const float4*>(W1 + t * 4);
        xs[t] = gelu_exact(w1r.z + w1r.w + b1[t]);
    }
    __syncthreads();

    // ---- Layer 2: neuron j ----
    if (w == 0) {
        float4 wv = *reinterpret_cast<const float4*>(W2 + (size_t)j * 256 + l * 4);
        float4 x4 = *reinterpret_cast<const float4*>(xs + l * 4);
        float r = wave_reduce(dot4(wv, x4));
        if (l == 0)
            __hip_atomic_store(&xA[j], gelu_exact(r + b2[j]),
                               __ATOMIC_RELEASE, __HIP_MEMORY_SCOPE_AGENT);
    }
    grid_barrier(bar + 0 * 32);

    // ---- Layer 3 ----
    xs[t] = __hip_atomic_load(&xA[t], __ATOMIC_ACQUIRE, __HIP_MEMORY_SCOPE_AGENT);
    __syncthreads();
    if (w == 0) {
        float4 wv = *reinterpret_cast<const float4*>(W3 + (size_t)j * 256 + l * 4);
        float4 x4 = *reinterpret_cast<const float4*>(xs + l * 4);
        float r = wave_reduce(dot4(wv, x4));
        if (l == 0)
            __hip_atomic_store(&xB[j], gelu_exact(r + b3[j]),
                               __ATOMIC_RELEASE, __HIP_MEMORY_SCOPE_AGENT);
    }
    grid_barrier(bar + 1 * 32);

    // ---- Layer 4 ----
    xs[t] = __hip_atomic_load(&xB[t], __ATOMIC_ACQUIRE, __HIP_MEMORY_SCOPE_AGENT);
    __syncthreads();
    if (w == 0) {
        float4 wv = *reinterpret_cast<const float4*>(W4 + (size_t)j * 256 + l * 4);
        float4 x4 = *reinterpret_cast<const float4*>(xs + l * 4);
        float r = wave_reduce(dot4(wv, x4));
        if (l == 0)
            __hip_atomic_store(&xC[j], gelu_exact(r + b4[j]),
                               __ATOMIC_RELEASE, __HIP_MEMORY_SCOPE_AGENT);
    }
    grid_barrier(bar + 2 * 32);

    // ---- Layer 5: W5 [12,256], no activation; blocks 0..11 ----
    xs[t] = __hip_atomic_load(&xC[t], __ATOMIC_ACQUIRE, __HIP_MEMORY_SCOPE_AGENT);
    __syncthreads();
    if (j < 12 && w == 0) {
        float4 wv = *reinterpret_cast<const float4*>(W5 + (size_t)j * 256 + l * 4);
        float4 x4 = *reinterpret_cast<const float4*>(xs + l * 4);
        float r = wave_reduce(dot4(wv, x4));
        if (l == 0)
            __hip_atomic_store(&wout[j], r + b5[j],
                               __ATOMIC_RELEASE, __HIP_MEMORY_SCOPE_AGENT);
    }
    grid_barrier(bar + 3 * 32);

    // ---- Apply: pred[b,p,d] = sum_c feat[b,c,p] * w[c*3+d] ----
    if (t < 12)
        wl[t] = __hip_atomic_load(&wout[t], __ATOMIC_ACQUIRE, __HIP_MEMORY_SCOPE_AGENT);
    __syncthreads();

    const int idx = j * 256 + t;              // 0..65535 quad index
    const int b   = idx >> 14;                // batch
    const int pos = (idx & 16383) << 2;       // pixel start (multiple of 4)

    const float* fb = feat + (size_t)b * 4 * 65536 + pos;
    const float4 f0 = *reinterpret_cast<const float4*>(fb);
    const float4 f1 = *reinterpret_cast<const float4*>(fb + 65536);
    const float4 f2 = *reinterpret_cast<const float4*>(fb + 131072);
    const float4 f3 = *reinterpret_cast<const float4*>(fb + 196608);

    float wr[12];
    #pragma unroll
    for (int i = 0; i < 12; ++i) wr[i] = wl[i];

    float r[12];
    #pragma unroll
    for (int dd = 0; dd < 3; ++dd) {
        r[0 + dd] = f0.x * wr[dd] + f1.x * wr[3 + dd] + f2.x * wr[6 + dd] + f3.x * wr[9 + dd];
        r[3 + dd] = f0.y * wr[dd] + f1.y * wr[3 + dd] + f2.y * wr[6 + dd] + f3.y * wr[9 + dd];
        r[6 + dd] = f0.z * wr[dd] + f1.z * wr[3 + dd] + f2.z * wr[6 + dd] + f3.z * wr[9 + dd];
        r[9 + dd] = f0.w * wr[dd] + f1.w * wr[3 + dd] + f2.w * wr[6 + dd] + f3.w * wr[9 + dd];
    }

    float* op = out + (size_t)(b * 65536 + pos) * 3;
    reinterpret_cast<float4*>(op)[0] = make_float4(r[0], r[1], r[2],  r[3]);
    reinterpret_cast<float4*>(op)[1] = make_float4(r[4], r[5], r[6],  r[7]);
    reinterpret_cast<float4*>(op)[2] = make_float4(r[8], r[9], r[10], r[11]);
}

extern "C" void kernel_launch(void* const* d_in, const int* in_sizes, int n_in,
                              void* d_out, int out_size, void* d_ws, size_t ws_size,
                              hipStream_t stream) {
    const float* feat = (const float*)d_in[0];
    const float* W1   = (const float*)d_in[1];
    const float* b1   = (const float*)d_in[2];
    const float* W2   = (const float*)d_in[3];
    const float* b2   = (const float*)d_in[4];
    const float* W3   = (const float*)d_in[5];
    const float* b3   = (const float*)d_in[6];
    const float* W4   = (const float*)d_in[7];
    const float* b4   = (const float*)d_in[8];
    const float* W5   = (const float*)d_in[9];
    const float* b5   = (const float*)d_in[10];

    float* out = (float*)d_out;   // [4, 65536, 3] fp32
    float* ws  = (float*)d_ws;

    fused_kernel<<<NBLK, 256, 0, stream>>>(W1, b1, W2, b2, W3, b3, W4, b4,
                                           W5, b5, feat, out, ws);
}

// Round 11
// 98.481 us; speedup vs baseline: 1.6157x; 1.6157x over previous
//
#include <hip/hip_runtime.h>

// Exact (non-approximate) GELU, matching jax.nn.gelu(approximate=False).
__device__ __forceinline__ float gelu_exact(float x) {
    return 0.5f * x * (1.0f + erff(x * 0.7071067811865475f));
}

__device__ __forceinline__ float dot4(float4 a, float4 b) {
    return a.x * b.x + a.y * b.y + a.z * b.z + a.w * b.w;
}

// One kernel, 256 blocks x 256 threads, ZERO inter-block communication.
// Every block redundantly evaluates the 5-layer MLP at the constant input
// [0,0,1,1] (weights become L2-resident per XCD after first touch; HBM cost
// is only ~770KB x 8 XCDs), then applies its 1/256 slice of the output.
//
// Layer layout (256x256): 4 lanes per neuron, 16 neurons per wave-tile.
//   lane l: neuron-in-tile = l>>2, k-slice s = l&3.
//   Thread reads W[n*256 + s*4 + m*16 .. +3] for m=0..15 — each 4-lane
//   cluster covers one full 64B cacheline per instruction (line-granular
//   efficiency from L2), and the reduce is only 2 shfl_xor steps (the
//   6-step 64-lane butterfly chains were r8's hidden 30us cost).
// x ping-pongs between two LDS buffers: one __syncthreads per layer.
#define LAYER256(WIN, BIN, XIN, XOUT)                                        \
    {                                                                        \
        _Pragma("unroll")                                                    \
        for (int tile = 0; tile < 4; ++tile) {                               \
            const int n = w * 64 + tile * 16 + nclub;                        \
            const float* row = (WIN) + (size_t)n * 256 + s * 4;              \
            float acc = 0.f;                                                 \
            _Pragma("unroll")                                                \
            for (int m = 0; m < 16; ++m) {                                   \
                float4 wv = *reinterpret_cast<const float4*>(row + m * 16);  \
                float4 xv = *reinterpret_cast<const float4*>((XIN) + s * 4 + m * 16); \
                acc += dot4(wv, xv);                                         \
            }                                                                \
            acc += __shfl_xor(acc, 1);                                       \
            acc += __shfl_xor(acc, 2);                                       \
            if (s == 0) (XOUT)[n] = gelu_exact(acc + (BIN)[n]);              \
        }                                                                    \
        __syncthreads();                                                     \
    }

__global__ __launch_bounds__(256) void fused2_kernel(
    const float* __restrict__ W1, const float* __restrict__ b1,
    const float* __restrict__ W2, const float* __restrict__ b2,
    const float* __restrict__ W3, const float* __restrict__ b3,
    const float* __restrict__ W4, const float* __restrict__ b4,
    const float* __restrict__ W5, const float* __restrict__ b5,
    const float* __restrict__ feat, float* __restrict__ out)
{
    __shared__ __align__(16) float xA[256];
    __shared__ __align__(16) float xB[256];

    const int t = threadIdx.x;
    const int w = t >> 6;        // wave 0..3
    const int l = t & 63;        // lane
    const int nclub = l >> 2;    // neuron-within-tile 0..15
    const int s = l & 3;         // k-slice 0..3

    // ---- Layer 1: input [0,0,1,1]; W1 [256,4] row-major (coalesced) ----
    {
        float4 w1r = *reinterpret_cast<const float4*>(W1 + t * 4);
        xA[t] = gelu_exact(w1r.z + w1r.w + b1[t]);
    }
    __syncthreads();

    LAYER256(W2, b2, xA, xB)     // x2 -> xB
    LAYER256(W3, b3, xB, xA)     // x3 -> xA
    LAYER256(W4, b4, xA, xB)     // x4 -> xB

    // ---- Layer 5: W5 [12,256], no activation. 12 neurons x 4 lanes ----
    if (w == 0 && nclub < 12) {  // lanes 0..47 of wave 0
        const float* row = W5 + (size_t)nclub * 256 + s * 4;
        float acc = 0.f;
        #pragma unroll
        for (int m = 0; m < 16; ++m) {
            float4 wv = *reinterpret_cast<const float4*>(row + m * 16);
            float4 xv = *reinterpret_cast<const float4*>(xB + s * 4 + m * 16);
            acc += dot4(wv, xv);
        }
        acc += __shfl_xor(acc, 1);
        acc += __shfl_xor(acc, 2);
        if (s == 0) xA[nclub] = acc + b5[nclub];   // park w[0..11] in xA
    }
    __syncthreads();

    // ---- Apply: pred[b,p,d] = sum_c feat[b,c,p] * w[c*3+d] ----
    float wr[12];
    #pragma unroll
    for (int i = 0; i < 12; ++i) wr[i] = xA[i];    // LDS broadcast reads

    const int idx = blockIdx.x * 256 + t;          // 0..65535 quad index
    const int b   = idx >> 14;                     // batch
    const int pos = (idx & 16383) << 2;            // pixel start (x4)

    const float* fb = feat + (size_t)b * 4 * 65536 + pos;
    const float4 f0 = *reinterpret_cast<const float4*>(fb);
    const float4 f1 = *reinterpret_cast<const float4*>(fb + 65536);
    const float4 f2 = *reinterpret_cast<const float4*>(fb + 131072);
    const float4 f3 = *reinterpret_cast<const float4*>(fb + 196608);

    float r[12];
    #pragma unroll
    for (int dd = 0; dd < 3; ++dd) {
        r[0 + dd] = f0.x * wr[dd] + f1.x * wr[3 + dd] + f2.x * wr[6 + dd] + f3.x * wr[9 + dd];
        r[3 + dd] = f0.y * wr[dd] + f1.y * wr[3 + dd] + f2.y * wr[6 + dd] + f3.y * wr[9 + dd];
        r[6 + dd] = f0.z * wr[dd] + f1.z * wr[3 + dd] + f2.z * wr[6 + dd] + f3.z * wr[9 + dd];
        r[9 + dd] = f0.w * wr[dd] + f1.w * wr[3 + dd] + f2.w * wr[6 + dd] + f3.w * wr[9 + dd];
    }

    float* op = out + (size_t)(b * 65536 + pos) * 3;
    reinterpret_cast<float4*>(op)[0] = make_float4(r[0], r[1], r[2],  r[3]);
    reinterpret_cast<float4*>(op)[1] = make_float4(r[4], r[5], r[6],  r[7]);
    reinterpret_cast<float4*>(op)[2] = make_float4(r[8], r[9], r[10], r[11]);
}

extern "C" void kernel_launch(void* const* d_in, const int* in_sizes, int n_in,
                              void* d_out, int out_size, void* d_ws, size_t ws_size,
                              hipStream_t stream) {
    const float* feat = (const float*)d_in[0];
    const float* W1   = (const float*)d_in[1];
    const float* b1   = (const float*)d_in[2];
    const float* W2   = (const float*)d_in[3];
    const float* b2   = (const float*)d_in[4];
    const float* W3   = (const float*)d_in[5];
    const float* b3   = (const float*)d_in[6];
    const float* W4   = (const float*)d_in[7];
    const float* b4   = (const float*)d_in[8];
    const float* W5   = (const float*)d_in[9];
    const float* b5   = (const float*)d_in[10];

    float* out = (float*)d_out;   // [4, 65536, 3] fp32

    fused2_kernel<<<256, 256, 0, stream>>>(W1, b1, W2, b2, W3, b3, W4, b4,
                                           W5, b5, feat, out);
}